// Round 1
// baseline (235.550 us; speedup 1.0000x reference)
//
#include <hip/hip_runtime.h>

// Problem constants (from reference): B=64 batches, grid 64^3, P=4096 points.
#define BB 64
#define NDIM 64
#define GRID3 (NDIM * NDIM * NDIM)   // 262144 bins per batch
#define NPTS 4096

// Kernel 1: histogram scatter. One thread per (b, p) point.
__global__ __launch_bounds__(256) void hist_kernel(const float* __restrict__ z,
                                                   float* __restrict__ counts) {
    int t = blockIdx.x * blockDim.x + threadIdx.x;   // 0 .. BB*NPTS-1
    int b = t >> 12;                                  // t / 4096
    const float* zp = z + (size_t)t * 3;
    float z0 = zp[0], z1 = zp[1], z2 = zp[2];
    // idx = clip(floor(z * 64), 0, 63)  (ranges are [0,1))
    int i0 = (int)floorf(z0 * 64.0f);
    int i1 = (int)floorf(z1 * 64.0f);
    int i2 = (int)floorf(z2 * 64.0f);
    i0 = min(max(i0, 0), 63);
    i1 = min(max(i1, 0), 63);
    i2 = min(max(i2, 0), 63);
    int lin = (i0 << 12) | (i1 << 6) | i2;           // i0*4096 + i1*64 + i2
    atomicAdd(&counts[(size_t)b * GRID3 + lin], 1.0f);
}

// Kernel 2: per-row (length-64, last dim) reverse inclusive cumsum + mask.
// One wave64 per row; lane = last-dim index. In-place update of counts is
// safe: each wave owns its row, reads before writing, wave-synchronous.
__global__ __launch_bounds__(256) void suffix_mask_kernel(const float* __restrict__ x,
                                                          float* __restrict__ counts,
                                                          float* __restrict__ rm) {
    int gtid = blockIdx.x * blockDim.x + threadIdx.x;
    int lane = threadIdx.x & 63;
    int idx  = gtid;                                  // row*64 + lane (rows contiguous)

    float c = counts[idx];

    // Inclusive prefix scan across the 64-lane wave.
    float p = c;
    #pragma unroll
    for (int d = 1; d < 64; d <<= 1) {
        float n = __shfl_up(p, d, 64);
        if (lane >= d) p += n;
    }
    float total = __shfl(p, 63, 64);

    // suffix-inclusive sum: c + total - inclusive_prefix
    float s = c + total - p;

    counts[idx] = s;
    rm[idx] = (s > 0.0f) ? x[idx] : 0.0f;
}

extern "C" void kernel_launch(void* const* d_in, const int* in_sizes, int n_in,
                              void* d_out, int out_size, void* d_ws, size_t ws_size,
                              hipStream_t stream) {
    const float* x = (const float*)d_in[0];   // [BB, 64,64,64]
    const float* z = (const float*)d_in[1];   // [BB, NPTS, 3]

    float* counts = (float*)d_out;                        // output 0: [BB, 64,64,64]
    float* rm     = counts + (size_t)BB * GRID3;          // output 1: same shape

    // Zero the counts half (d_out is poisoned 0xAA before every timed call).
    hipMemsetAsync(counts, 0, (size_t)BB * GRID3 * sizeof(float), stream);

    // Histogram: BB*NPTS = 262144 points.
    hist_kernel<<<(BB * NPTS) / 256, 256, 0, stream>>>(z, counts);

    // Suffix-sum + mask: BB*GRID3 = 16,777,216 elements, 4 rows per 256-thread block.
    suffix_mask_kernel<<<(BB * GRID3) / 256, 256, 0, stream>>>(x, counts, rm);
}

// Round 2
// 215.558 us; speedup vs baseline: 1.0927x; 1.0927x over previous
//
#include <hip/hip_runtime.h>

// Problem constants (from reference): B=64 batches, grid 64^3, P=4096 points.
#define BB 64
#define NDIM 64
#define GRID3 (NDIM * NDIM * NDIM)   // 262144 bins per batch
#define NPTS 4096

// Fused kernel: one block per (batch b, slab i0).
//  - LDS 64x64 u32 histogram over (i1,i2) for this slab
//  - scan all 4096 points of batch b (z[b] = 48 KB, L2-resident; filter on z0
//    before touching z1/z2)
//  - per-wave shfl suffix-scan each 64-long i2 row, write counts + masked x
// No global intermediate, no memset, no global atomics.
__global__ __launch_bounds__(256) void fused_kernel(const float* __restrict__ x,
                                                    const float* __restrict__ z,
                                                    float* __restrict__ counts,
                                                    float* __restrict__ rm) {
    __shared__ unsigned int H[NDIM * NDIM];   // 16 KB

    const int slab = blockIdx.x;   // i0
    const int b    = blockIdx.y;
    const int tid  = threadIdx.x;

    // 1. zero LDS histogram
    #pragma unroll
    for (int i = 0; i < 16; ++i) H[tid + i * 256] = 0u;
    __syncthreads();

    // 2. scan this batch's points, filter by slab, LDS-atomic increment
    const float* zb = z + (size_t)b * NPTS * 3;
    #pragma unroll 4
    for (int i = 0; i < 16; ++i) {
        int p = i * 256 + tid;
        float z0 = zb[p * 3 + 0];
        int i0 = min(max((int)floorf(z0 * 64.0f), 0), 63);
        if (i0 == slab) {
            float z1 = zb[p * 3 + 1];
            float z2 = zb[p * 3 + 2];
            int i1 = min(max((int)floorf(z1 * 64.0f), 0), 63);
            int i2 = min(max((int)floorf(z2 * 64.0f), 0), 63);
            atomicAdd(&H[(i1 << 6) | i2], 1u);
        }
    }
    __syncthreads();

    // 3. per-row suffix sum (lane = i2), write outputs coalesced
    const int lane = tid & 63;
    const int wave = tid >> 6;
    const size_t base = ((size_t)b << 18) + ((size_t)slab << 12);

    #pragma unroll
    for (int r = 0; r < 16; ++r) {
        int row = wave * 16 + r;
        float c = (float)H[(row << 6) | lane];   // bank = lane%32: 2-way, free

        // inclusive prefix scan across the 64-lane wave
        float pr = c;
        #pragma unroll
        for (int d = 1; d < 64; d <<= 1) {
            float n = __shfl_up(pr, d, 64);
            if (lane >= d) pr += n;
        }
        float total = __shfl(pr, 63, 64);
        float s = c + total - pr;               // reverse inclusive cumsum (exact: small ints)

        size_t idx = base + ((size_t)row << 6) + lane;
        counts[idx] = s;
        float xv = 0.0f;
        if (s > 0.0f) xv = x[idx];              // skip load where mask is 0
        rm[idx] = xv;
    }
}

extern "C" void kernel_launch(void* const* d_in, const int* in_sizes, int n_in,
                              void* d_out, int out_size, void* d_ws, size_t ws_size,
                              hipStream_t stream) {
    const float* x = (const float*)d_in[0];   // [BB, 64,64,64]
    const float* z = (const float*)d_in[1];   // [BB, NPTS, 3]

    float* counts = (float*)d_out;                        // output 0
    float* rm     = counts + (size_t)BB * GRID3;          // output 1

    dim3 grid(NDIM, BB);   // x = slab (i0), y = batch
    fused_kernel<<<grid, 256, 0, stream>>>(x, z, counts, rm);
}

// Round 3
// 211.530 us; speedup vs baseline: 1.1136x; 1.0190x over previous
//
#include <hip/hip_runtime.h>

// Problem constants (from reference): B=64 batches, grid 64^3, P=4096 points.
#define BB 64
#define NDIM 64
#define GRID3 (NDIM * NDIM * NDIM)   // 262144 bins per batch
#define NPTS 4096

// Fused kernel: one block per (batch b, slab i0).
// Round-3 change: force ILP everywhere (R2 compiled to VGPR=12, zero ILP,
// latency-bound at 20% HBM / 17% VALU).
__global__ __launch_bounds__(256) void fused_kernel(const float* __restrict__ x,
                                                    const float* __restrict__ z,
                                                    float* __restrict__ counts,
                                                    float* __restrict__ rm) {
    __shared__ unsigned int H[NDIM * NDIM];   // 16 KB (i1,i2) histogram

    const int slab = blockIdx.x;   // i0
    const int b    = blockIdx.y;
    const int tid  = threadIdx.x;

    // 1. zero LDS histogram, vectorized (4 × uint4 stores per thread)
    uint4* H4 = (uint4*)H;
    #pragma unroll
    for (int i = 0; i < 4; ++i) H4[tid + i * 256] = make_uint4(0u, 0u, 0u, 0u);
    __syncthreads();

    // 2. scan this batch's points. Prefetch all 16 z0 coords first so 16
    //    independent loads are in flight (R2 had them in a serial chain).
    const float* zb = z + (size_t)b * NPTS * 3;
    float z0v[16];
    #pragma unroll
    for (int i = 0; i < 16; ++i) z0v[i] = zb[(size_t)(i * 256 + tid) * 3];

    #pragma unroll
    for (int i = 0; i < 16; ++i) {
        int i0 = min(max((int)floorf(z0v[i] * 64.0f), 0), 63);
        if (i0 == slab) {
            int p = i * 256 + tid;
            float z1 = zb[p * 3 + 1];
            float z2 = zb[p * 3 + 2];
            int i1 = min(max((int)floorf(z1 * 64.0f), 0), 63);
            int i2 = min(max((int)floorf(z2 * 64.0f), 0), 63);
            atomicAdd(&H[(i1 << 6) | i2], 1u);
        }
    }
    __syncthreads();

    // 3. per-row suffix sum (lane = i2). Each wave owns 16 rows; scan-step
    //    loop OUTER, row loop INNER -> 16-way ILP between bpermutes.
    const int lane = tid & 63;
    const int wave = tid >> 6;
    const size_t base = ((size_t)b << 18) + ((size_t)slab << 12) + ((size_t)wave << 10);

    float c[16], pr[16];
    #pragma unroll
    for (int r = 0; r < 16; ++r) {
        c[r]  = (float)H[((wave * 16 + r) << 6) | lane];   // 2-way bank alias: free
        pr[r] = c[r];
    }

    #pragma unroll
    for (int d = 1; d < 64; d <<= 1) {
        #pragma unroll
        for (int r = 0; r < 16; ++r) {
            float n = __shfl_up(pr[r], d, 64);
            if (lane >= d) pr[r] += n;
        }
    }

    // 4. epilogue: counts + masked x. Wave-uniform skip of x load for empty
    //    rows (~37%); nonempty rows load coalesced, independent across rows.
    #pragma unroll
    for (int r = 0; r < 16; ++r) {
        float total = __shfl(pr[r], 63, 64);
        float s = c[r] + total - pr[r];        // reverse inclusive cumsum (exact)
        size_t idx = base + (r << 6) + lane;
        counts[idx] = s;
        float xv = 0.0f;
        if (total > 0.0f) xv = x[idx];         // wave-uniform branch
        rm[idx] = (s > 0.0f) ? xv : 0.0f;
    }
}

extern "C" void kernel_launch(void* const* d_in, const int* in_sizes, int n_in,
                              void* d_out, int out_size, void* d_ws, size_t ws_size,
                              hipStream_t stream) {
    const float* x = (const float*)d_in[0];   // [BB, 64,64,64]
    const float* z = (const float*)d_in[1];   // [BB, NPTS, 3]

    float* counts = (float*)d_out;                        // output 0
    float* rm     = counts + (size_t)BB * GRID3;          // output 1

    dim3 grid(NDIM, BB);   // x = slab (i0), y = batch
    fused_kernel<<<grid, 256, 0, stream>>>(x, z, counts, rm);
}

// Round 4
// 209.032 us; speedup vs baseline: 1.1269x; 1.0119x over previous
//
#include <hip/hip_runtime.h>

// Problem constants (from reference): B=64 batches, grid 64^3, P=4096 points.
#define BB 64
#define NDIM 64
#define GRID3 (NDIM * NDIM * NDIM)   // 262144 bins per batch
#define NPTS 4096

// Fused kernel: one block per (batch b, slab i0).
// R4: segmented register scan. R2/R3 were ds-latency-bound: 64 wave-scans
// = ~112 serial bpermutes/wave (VGPR=28 forced row-serial chains). Now each
// thread scans 16 bins in registers; only 3 bpermutes on the critical path.
__global__ __launch_bounds__(256) void fused_kernel(const float* __restrict__ x,
                                                    const float* __restrict__ z,
                                                    float* __restrict__ counts,
                                                    float* __restrict__ rm) {
    __shared__ unsigned int H[NDIM * NDIM];   // 16 KB (i1,i2) histogram

    const int slab = blockIdx.x;   // i0
    const int b    = blockIdx.y;
    const int tid  = threadIdx.x;

    // 1. zero LDS histogram, vectorized
    uint4* H4 = (uint4*)H;
    #pragma unroll
    for (int i = 0; i < 4; ++i) H4[tid + i * 256] = make_uint4(0u, 0u, 0u, 0u);
    __syncthreads();

    // 2. scan this batch's points; prefetch z0 (16 independent loads in flight)
    const float* zb = z + (size_t)b * NPTS * 3;
    float z0v[16];
    #pragma unroll
    for (int i = 0; i < 16; ++i) z0v[i] = zb[(size_t)(i * 256 + tid) * 3];

    #pragma unroll
    for (int i = 0; i < 16; ++i) {
        int i0 = min(max((int)floorf(z0v[i] * 64.0f), 0), 63);
        if (i0 == slab) {
            int p = i * 256 + tid;
            float z1 = zb[p * 3 + 1];
            float z2 = zb[p * 3 + 2];
            int i1 = min(max((int)floorf(z1 * 64.0f), 0), 63);
            int i2 = min(max((int)floorf(z2 * 64.0f), 0), 63);
            atomicAdd(&H[(i1 << 6) | i2], 1u);
        }
    }
    __syncthreads();

    // 3. segmented suffix scan. Thread owns a quarter-row: row = tid>>2,
    //    bins [seg*16, seg*16+16). 4x ds_read_b128 (16B/lane contiguous =
    //    conflict-free), register prefix, 2-step shfl over 4-lane segments.
    {
        const int row = tid >> 2;
        const int seg = tid & 3;
        const int q4  = (row << 4) + (seg << 2);   // uint4 index of segment start

        float e[16], pr[16];
        #pragma unroll
        for (int i = 0; i < 4; ++i) {
            uint4 q = H4[q4 + i];
            e[4*i+0] = (float)q.x; e[4*i+1] = (float)q.y;
            e[4*i+2] = (float)q.z; e[4*i+3] = (float)q.w;
        }
        float p = 0.0f;
        #pragma unroll
        for (int j = 0; j < 16; ++j) { p += e[j]; pr[j] = p; }
        const float seg_sum = p;

        // inclusive scan of seg_sum over the 4-lane group
        float sc = seg_sum;
        float n1 = __shfl_up(sc, 1, 4); if ((tid & 3) >= 1) sc += n1;
        float n2 = __shfl_up(sc, 2, 4); if ((tid & 3) >= 2) sc += n2;
        const float T       = __shfl(sc, 3, 4);   // row total
        const float segExcl = sc - seg_sum;       // prefix before this segment

        // suffix s_j = e_j + T - inclusive_prefix_j ; write back (own bins)
        float4* Hf4 = (float4*)H;
        #pragma unroll
        for (int i = 0; i < 4; ++i) {
            float4 w;
            w.x = e[4*i+0] + T - (segExcl + pr[4*i+0]);
            w.y = e[4*i+1] + T - (segExcl + pr[4*i+1]);
            w.z = e[4*i+2] + T - (segExcl + pr[4*i+2]);
            w.w = e[4*i+3] + T - (segExcl + pr[4*i+3]);
            Hf4[q4 + i] = w;
        }
    }
    __syncthreads();

    // 4. coalesced output: lane = i2. s is non-increasing along lane, so the
    //    s>0 predicated x-load keeps active lanes a contiguous prefix.
    const int lane = tid & 63;
    const int wave = tid >> 6;
    const float* Hf = (const float*)H;
    const size_t base = ((size_t)b << 18) + ((size_t)slab << 12) + ((size_t)wave << 10);

    #pragma unroll
    for (int r = 0; r < 16; ++r) {
        float s = Hf[((wave * 16 + r) << 6) | lane];   // 2-way alias: free
        size_t idx = base + (r << 6) + lane;
        counts[idx] = s;
        float xv = 0.0f;
        if (s > 0.0f) xv = x[idx];
        rm[idx] = xv;
    }
}

extern "C" void kernel_launch(void* const* d_in, const int* in_sizes, int n_in,
                              void* d_out, int out_size, void* d_ws, size_t ws_size,
                              hipStream_t stream) {
    const float* x = (const float*)d_in[0];   // [BB, 64,64,64]
    const float* z = (const float*)d_in[1];   // [BB, NPTS, 3]

    float* counts = (float*)d_out;                        // output 0
    float* rm     = counts + (size_t)BB * GRID3;          // output 1

    dim3 grid(NDIM, BB);   // x = slab (i0), y = batch
    fused_kernel<<<grid, 256, 0, stream>>>(x, z, counts, rm);
}

// Round 5
// 195.488 us; speedup vs baseline: 1.2049x; 1.0693x over previous
//
#include <hip/hip_runtime.h>

// Problem constants (from reference): B=64 batches, grid 64^3, P=4096 points.
#define BB 64
#define NDIM 64
#define GRID3 (NDIM * NDIM * NDIM)   // 262144 bins per batch
#define NPTS 4096

// d_ws layout: [0,16KB) u32 slab counters (BB*64), [16KB, 16KB+32MB) u16 lists
// (4096 slots per (b,slab) — worst case all points of a batch in one slab).

// Kernel 1: visit each point ONCE, compact into per-(b,slab) u16 lists.
// (R2-R4 had every one of 64 slab-blocks re-scan all 4096 points: 64x
// redundant stride-12 loads ~= 20 us of TA occupancy. This kernel does the
// binning once: 3 MB of reads total.)
__global__ __launch_bounds__(256) void bin_kernel(const float* __restrict__ z,
                                                  unsigned int* __restrict__ cnt,
                                                  unsigned short* __restrict__ list) {
    int t = blockIdx.x * 256 + threadIdx.x;   // 0 .. BB*NPTS-1
    int b = t >> 12;
    const float* zp = z + (size_t)t * 3;
    float z0 = zp[0], z1 = zp[1], z2 = zp[2];
    int i0 = min(max((int)floorf(z0 * 64.0f), 0), 63);
    int i1 = min(max((int)floorf(z1 * 64.0f), 0), 63);
    int i2 = min(max((int)floorf(z2 * 64.0f), 0), 63);
    int sb = (b << 6) | i0;
    unsigned int slot = atomicAdd(&cnt[sb], 1u);
    list[((size_t)sb << 12) | slot] = (unsigned short)((i1 << 6) | i2);
}

// Kernel 2: one block per (batch b, slab i0). LDS histogram from the compact
// list (~64 points), segmented register suffix-scan, float4 output pass.
__global__ __launch_bounds__(256) void fused_kernel(const float* __restrict__ x,
                                                    const unsigned int* __restrict__ cnt,
                                                    const unsigned short* __restrict__ list,
                                                    float* __restrict__ counts,
                                                    float* __restrict__ rm) {
    __shared__ unsigned int H[NDIM * NDIM];   // 16 KB (i1,i2) histogram

    const int slab = blockIdx.x;   // i0
    const int b    = blockIdx.y;
    const int tid  = threadIdx.x;
    const int sb   = (b << 6) | slab;

    // 1. zero LDS histogram (uint4)
    uint4* H4 = (uint4*)H;
    #pragma unroll
    for (int i = 0; i < 4; ++i) H4[tid + i * 256] = make_uint4(0u, 0u, 0u, 0u);
    __syncthreads();

    // 2. histogram this slab's compact point list (mean ~64 entries)
    const int n = (int)cnt[sb];
    const unsigned short* lp = list + ((size_t)sb << 12);
    for (int p = tid; p < n; p += 256)
        atomicAdd(&H[lp[p]], 1u);
    __syncthreads();

    // 3. segmented suffix scan: thread owns a quarter-row (16 bins, 4x b128),
    //    register prefix, 2-step shfl across the 4-lane segment group.
    {
        const int row = tid >> 2;
        const int seg = tid & 3;
        const int q4  = (row << 4) + (seg << 2);

        float e[16], pr[16];
        #pragma unroll
        for (int i = 0; i < 4; ++i) {
            uint4 q = H4[q4 + i];
            e[4*i+0] = (float)q.x; e[4*i+1] = (float)q.y;
            e[4*i+2] = (float)q.z; e[4*i+3] = (float)q.w;
        }
        float p = 0.0f;
        #pragma unroll
        for (int j = 0; j < 16; ++j) { p += e[j]; pr[j] = p; }
        const float seg_sum = p;

        float sc = seg_sum;
        float n1 = __shfl_up(sc, 1, 4); if (seg >= 1) sc += n1;
        float n2 = __shfl_up(sc, 2, 4); if (seg >= 2) sc += n2;
        const float T       = __shfl(sc, 3, 4);   // row total
        const float segExcl = sc - seg_sum;

        float4* Hf4 = (float4*)H;
        #pragma unroll
        for (int i = 0; i < 4; ++i) {
            float4 w;
            w.x = e[4*i+0] + T - (segExcl + pr[4*i+0]);
            w.y = e[4*i+1] + T - (segExcl + pr[4*i+1]);
            w.z = e[4*i+2] + T - (segExcl + pr[4*i+2]);
            w.w = e[4*i+3] + T - (segExcl + pr[4*i+3]);
            Hf4[q4 + i] = w;
        }
    }
    __syncthreads();

    // 4. float4 output pass: 16 B/lane loads+stores (4x fewer memory
    //    instructions than R4's scalar pass). s non-increasing within a row
    //    and each float4 sits inside one row, so s.x>0 predicates the quad.
    const float4* Hs = (const float4*)H;
    const float4* x4 = (const float4*)x;
    float4* c4 = (float4*)counts;
    float4* r4 = (float4*)rm;
    const size_t base4 = ((size_t)b << 16) + ((size_t)slab << 10);   // float4 units

    #pragma unroll
    for (int i = 0; i < 4; ++i) {
        int j = tid + i * 256;            // 0..1023
        float4 s = Hs[j];
        size_t idx = base4 + j;
        c4[idx] = s;
        float4 xv = make_float4(0.f, 0.f, 0.f, 0.f);
        if (s.x > 0.0f) xv = x4[idx];     // quad-predicated x read
        float4 r;
        r.x = (s.x > 0.0f) ? xv.x : 0.0f;
        r.y = (s.y > 0.0f) ? xv.y : 0.0f;
        r.z = (s.z > 0.0f) ? xv.z : 0.0f;
        r.w = (s.w > 0.0f) ? xv.w : 0.0f;
        r4[idx] = r;
    }
}

extern "C" void kernel_launch(void* const* d_in, const int* in_sizes, int n_in,
                              void* d_out, int out_size, void* d_ws, size_t ws_size,
                              hipStream_t stream) {
    const float* x = (const float*)d_in[0];   // [BB, 64,64,64]
    const float* z = (const float*)d_in[1];   // [BB, NPTS, 3]

    float* counts = (float*)d_out;                        // output 0
    float* rm     = counts + (size_t)BB * GRID3;          // output 1

    unsigned int*   cnt  = (unsigned int*)d_ws;                       // 16 KB
    unsigned short* list = (unsigned short*)((char*)d_ws + 16384);    // 32 MB

    // zero the slab counters (ws is poisoned 0xAA before every timed call)
    hipMemsetAsync(cnt, 0, BB * 64 * sizeof(unsigned int), stream);

    bin_kernel<<<(BB * NPTS) / 256, 256, 0, stream>>>(z, cnt, list);

    dim3 grid(NDIM, BB);   // x = slab (i0), y = batch
    fused_kernel<<<grid, 256, 0, stream>>>(x, cnt, list, counts, rm);
}